// Round 1
// baseline (682.124 us; speedup 1.0000x reference)
//
#include <hip/hip_runtime.h>
#include <math.h>

// MultiScaleRetention forward, pure fp32 (threshold 2.2e-5 abs ~ 1.2e-4 rel -> no bf16).
// B=8 S=1024 D=512 H=8 DH=64. ~38.7 GFLOP fp32 -> VALU-bound (no fp32 MFMA on CDNA4).
#define B_ 8
#define S_ 1024
#define D_ 512
#define H_ 8
#define DH_ 64
#define M_ (B_*S_)   // 8192 rows

// ---------- X [M,512] -> Xt [512,M] (k-major A operand for all projection GEMMs) ----------
__global__ __launch_bounds__(256) void transpose_kernel(const float* __restrict__ X,
                                                        float* __restrict__ Xt) {
  __shared__ float t[64][65];
  const int m0 = blockIdx.x * 64, d0 = blockIdx.y * 64;
  const int tid = threadIdx.x;
#pragma unroll
  for (int i = 0; i < 4; ++i) {
    int idx = tid + i * 256;
    int r = idx >> 4, c = (idx & 15) * 4;           // r: m-local, c: d-local
    float4 v = *(const float4*)(X + (size_t)(m0 + r) * D_ + d0 + c);
    t[r][c] = v.x; t[r][c+1] = v.y; t[r][c+2] = v.z; t[r][c+3] = v.w;
  }
  __syncthreads();
#pragma unroll
  for (int i = 0; i < 4; ++i) {
    int idx = tid + i * 256;
    int r = idx >> 4, c = (idx & 15) * 4;           // r: d-local, c: m-local
    float4 v = make_float4(t[c][r], t[c+1][r], t[c+2][r], t[c+3][r]);
    *(float4*)(Xt + (size_t)(d0 + r) * M_ + m0 + c) = v;
  }
}

// ---------- xpos sin/cos tables: 4 x [1024][32] = cosQ | sinQ | cosK | sinK ----------
__global__ void xpos_table_kernel(float* __restrict__ tab) {
  int idx = blockIdx.x * 256 + threadIdx.x;         // 32768
  int s = idx >> 5, i = idx & 31;
  float sv = (2.0f * (float)i + 0.4f * 64.0f) / (1.4f * 64.0f);
  float p = (float)s / 512.0f;                      // SCALE_BASE
  float scale = powf(sv, p);
  float inv_freq = powf(10000.0f, -((float)i / 32.0f));
  float ang = (float)s * inv_freq;
  float sn = sinf(ang), cs = cosf(ang);
  tab[idx]          = cs * scale;
  tab[32768 + idx]  = sn * scale;
  tab[65536 + idx]  = cs / scale;
  tab[98304 + idx]  = sn / scale;
}

// ---------- GEMM: C = At^T * B.  At is k-major [512][8192]. 128x64 tile, 8x4 micro ----------
template<bool FUSED>
__global__ __launch_bounds__(256) void gemm_kernel(
    const float* __restrict__ At,
    const float* __restrict__ W0, const float* __restrict__ W1,
    const float* __restrict__ W2, const float* __restrict__ W3,
    float* __restrict__ O0, float* __restrict__ O1,
    float* __restrict__ O2, float* __restrict__ O3) {
  __shared__ float As[16][128];
  __shared__ float Bs[16][64];
  const int m0 = blockIdx.x * 128;
  const int n0g = blockIdx.y * 64;
  const float* Bp;
  float* Cp;
  int ldb, cmode = 0, h = 0, ncol = 0;
  if constexpr (FUSED) {
    // columns 0..2047 span W_Q | W_K | W_V | W_G
    int w = n0g >> 9, n0 = n0g & 511;
    const float* Ws[4] = {W0, W1, W2, W3};
    float* Os[4] = {O0, O1, O2, O3};
    Cp = Os[w];
    if (w < 3) { h = n0 >> 6; Bp = Ws[w] + (size_t)h * D_ * DH_; ldb = DH_; cmode = 1; }
    else       { Bp = W3 + n0; ldb = D_; cmode = 0; ncol = n0; }
  } else {
    Bp = W0 + n0g; ldb = D_; Cp = O0; ncol = n0g;
  }
  const int tid = threadIdx.x, tx = tid & 15, ty = tid >> 4;
  float acc[8][4] = {};
  for (int k0 = 0; k0 < D_; k0 += 16) {
#pragma unroll
    for (int i = 0; i < 2; ++i) {
      int idx = tid + i * 256;
      int kk = idx >> 5, mm = (idx & 31) * 4;
      *(float4*)&As[kk][mm] = *(const float4*)(At + (size_t)(k0 + kk) * M_ + m0 + mm);
    }
    {
      int kk = tid >> 4, nn = (tid & 15) * 4;
      *(float4*)&Bs[kk][nn] = *(const float4*)(Bp + (size_t)(k0 + kk) * ldb + nn);
    }
    __syncthreads();
#pragma unroll
    for (int kk = 0; kk < 16; ++kk) {
      float4 a0 = *(const float4*)&As[kk][ty * 8];
      float4 a1 = *(const float4*)&As[kk][ty * 8 + 4];
      float4 b4 = *(const float4*)&Bs[kk][tx * 4];
      float ar[8] = {a0.x, a0.y, a0.z, a0.w, a1.x, a1.y, a1.z, a1.w};
      float br[4] = {b4.x, b4.y, b4.z, b4.w};
#pragma unroll
      for (int i = 0; i < 8; ++i)
#pragma unroll
        for (int j = 0; j < 4; ++j) acc[i][j] += ar[i] * br[j];
    }
    __syncthreads();
  }
#pragma unroll
  for (int i = 0; i < 8; ++i) {
    int r = m0 + ty * 8 + i;
    float4 v = make_float4(acc[i][0], acc[i][1], acc[i][2], acc[i][3]);
    size_t addr;
    if (cmode == 1) {
      int bb = r >> 10, s = r & 1023;   // Q/K/V layout [b,h,s,e]
      addr = (((size_t)(bb * H_ + h)) * S_ + s) * DH_ + tx * 4;
    } else {
      addr = (size_t)r * D_ + ncol + tx * 4;
    }
    *(float4*)(Cp + addr) = v;
  }
}

// ---------- xpos rotary + transpose: [bh][s][64] -> [bh][64][S] (e-major for attention) ----------
__global__ __launch_bounds__(256) void rotary_kernel(const float* __restrict__ Qin,
                                                     float* __restrict__ Qt,
                                                     const float* __restrict__ tab, int isK) {
  __shared__ float t[64][65];
  const int s0 = blockIdx.x * 64, bh = blockIdx.y;
  const float* ct = tab + (isK ? 65536 : 0);
  const float* st = tab + (isK ? 98304 : 32768);
  const int tid = threadIdx.x;
  const float* src = Qin + (size_t)bh * S_ * DH_;
#pragma unroll
  for (int i = 0; i < 4; ++i) {
    int idx = tid + i * 256;
    int r = idx >> 4, c = (idx & 15) * 4;           // r: s-local, c: e
    int s = s0 + r;
    float4 v = *(const float4*)(src + (size_t)s * DH_ + c);
    int i0 = c >> 1;                                 // pair index (c even)
    float c0 = ct[s * 32 + i0],     s0v = st[s * 32 + i0];
    float c1 = ct[s * 32 + i0 + 1], s1v = st[s * 32 + i0 + 1];
    t[c    ][r] = v.x * c0 - v.y * s0v;              // rotate_every_two
    t[c + 1][r] = v.y * c0 + v.x * s0v;
    t[c + 2][r] = v.z * c1 - v.w * s1v;
    t[c + 3][r] = v.w * c1 + v.z * s1v;
  }
  __syncthreads();
  float* dst = Qt + (size_t)bh * DH_ * S_;
#pragma unroll
  for (int i = 0; i < 4; ++i) {
    int idx = tid + i * 256;
    int e = idx >> 4, c = (idx & 15) * 4;            // e row, c: s-local
    float4 v = make_float4(t[e][c], t[e][c + 1], t[e][c + 2], t[e][c + 3]);
    *(float4*)(dst + (size_t)e * S_ + s0 + c) = v;
  }
}

// ---------- attention: online softmax * decay, one (b,h,64-row) block ----------
__global__ __launch_bounds__(256) void attn_kernel(const float* __restrict__ Qt,
                                                   const float* __restrict__ Kt,
                                                   const float* __restrict__ V,
                                                   float* __restrict__ Y) {
  __shared__ float Qe[64][64];   // [e][s]
  __shared__ float Ke[64][64];   // [e][t]
  __shared__ float Vs[64][64];   // [t][e]
  __shared__ float Ps[64][64];   // [s][t]  (total 64 KiB)
  const int s0 = blockIdx.x * 64, bh = blockIdx.y;
  const int b = bh >> 3, h = bh & 7;
  const int tid = threadIdx.x, tx = tid & 15, ty = tid >> 4;
  const float l0 = -3.4657359027997265f;   // ln(1/32)
  const float l1 = -6.2383246250395075f;   // ln(1/512)
  const float gamma = 1.0f - expf(l0 + (float)h * (l1 - l0) / 7.0f);
  const float lg2g = log2f(gamma);
  const float* Qp = Qt + (size_t)bh * DH_ * S_;
  const float* Kp = Kt + (size_t)bh * DH_ * S_;
  const float* Vp = V  + (size_t)bh * S_ * DH_;
#pragma unroll
  for (int i = 0; i < 4; ++i) {
    int idx = tid + i * 256;
    int e = idx >> 4, c = (idx & 15) * 4;
    *(float4*)&Qe[e][c] = *(const float4*)(Qp + (size_t)e * S_ + s0 + c);
  }
  float o[4][4] = {};
  float m_r[4], l_r[4];
#pragma unroll
  for (int i = 0; i < 4; ++i) { m_r[i] = -1e30f; l_r[i] = 0.0f; }

  for (int t0 = 0; t0 < S_; t0 += 64) {
    __syncthreads();                               // protect Ke/Vs (and Qe on iter 0)
#pragma unroll
    for (int i = 0; i < 4; ++i) {
      int idx = tid + i * 256;
      int e = idx >> 4, c = (idx & 15) * 4;
      *(float4*)&Ke[e][c] = *(const float4*)(Kp + (size_t)e * S_ + t0 + c);
      *(float4*)&Vs[e][c] = *(const float4*)(Vp + (size_t)(t0 + e) * DH_ + c);
    }
    __syncthreads();
    // scores: thread owns s rows ty*4.., t cols tx*4..
    float acc[4][4] = {};
#pragma unroll 16
    for (int e = 0; e < 64; ++e) {
      float4 q = *(const float4*)&Qe[e][ty * 4];
      float4 k = *(const float4*)&Ke[e][tx * 4];
      float qr[4] = {q.x, q.y, q.z, q.w};
      float kr[4] = {k.x, k.y, k.z, k.w};
#pragma unroll
      for (int i = 0; i < 4; ++i)
#pragma unroll
        for (int j = 0; j < 4; ++j) acc[i][j] += qr[i] * kr[j];
    }
    // online softmax; decay folded into P, denominator un-decayed (reference semantics)
#pragma unroll
    for (int i = 0; i < 4; ++i) {
      float rm = fmaxf(fmaxf(acc[i][0], acc[i][1]), fmaxf(acc[i][2], acc[i][3]));
      rm = fmaxf(rm, __shfl_xor(rm, 1));
      rm = fmaxf(rm, __shfl_xor(rm, 2));
      rm = fmaxf(rm, __shfl_xor(rm, 4));
      rm = fmaxf(rm, __shfl_xor(rm, 8));
      const float mnew = fmaxf(m_r[i], rm);
      float p[4];
      float rs = 0.0f;
#pragma unroll
      for (int j = 0; j < 4; ++j) { p[j] = expf(acc[i][j] - mnew); rs += p[j]; }
      rs += __shfl_xor(rs, 1);
      rs += __shfl_xor(rs, 2);
      rs += __shfl_xor(rs, 4);
      rs += __shfl_xor(rs, 8);
      const float alpha = expf(m_r[i] - mnew);
      l_r[i] = l_r[i] * alpha + rs;
      m_r[i] = mnew;
      const int srow = s0 + ty * 4 + i;
#pragma unroll
      for (int j = 0; j < 4; ++j) {
        o[i][j] *= alpha;
        p[j] *= exp2f(lg2g * fabsf((float)(srow - (t0 + tx * 4 + j))));
      }
      *(float4*)&Ps[ty * 4 + i][tx * 4] = make_float4(p[0], p[1], p[2], p[3]);
    }
    __syncthreads();
    // PV: thread owns s rows ty*4.., e cols tx*4..
#pragma unroll 8
    for (int t = 0; t < 64; ++t) {
      float4 v = *(const float4*)&Vs[t][tx * 4];
#pragma unroll
      for (int i = 0; i < 4; ++i) {
        const float p = Ps[ty * 4 + i][t];
        o[i][0] += p * v.x; o[i][1] += p * v.y; o[i][2] += p * v.z; o[i][3] += p * v.w;
      }
    }
  }
#pragma unroll
  for (int i = 0; i < 4; ++i) {
    const float inv = 1.0f / l_r[i];
    float4 v = make_float4(o[i][0] * inv, o[i][1] * inv, o[i][2] * inv, o[i][3] * inv);
    int srow = s0 + ty * 4 + i;
    *(float4*)(Y + ((size_t)(b * S_ + srow)) * D_ + h * DH_ + tx * 4) = v;
  }
}

// ---------- GroupNorm(H groups) + swish(G) gate + transpose -> Zt [512][8192] ----------
__global__ __launch_bounds__(256) void gn_gate_kernel(const float* __restrict__ Y,
                                                      const float* __restrict__ G,
                                                      const float* __restrict__ gnw,
                                                      const float* __restrict__ gnb,
                                                      float* __restrict__ Zt) {
  __shared__ float t[64][65];
  const int r0 = blockIdx.x * 64, h = blockIdx.y, d0 = h * DH_;
  const int tid = threadIdx.x, tx = tid & 15, tyq = tid >> 4;
  float4 wv = *(const float4*)(gnw + d0 + tx * 4);
  float4 bv = *(const float4*)(gnb + d0 + tx * 4);
  float w4[4] = {wv.x, wv.y, wv.z, wv.w};
  float b4[4] = {bv.x, bv.y, bv.z, bv.w};
#pragma unroll
  for (int i = 0; i < 4; ++i) {
    int r = r0 + tyq + i * 16;
    float4 yv = *(const float4*)(Y + (size_t)r * D_ + d0 + tx * 4);
    float y[4] = {yv.x, yv.y, yv.z, yv.w};
    float s = y[0] + y[1] + y[2] + y[3];
    s += __shfl_xor(s, 1); s += __shfl_xor(s, 2); s += __shfl_xor(s, 4); s += __shfl_xor(s, 8);
    const float mu = s * (1.0f / 64.0f);
    float d0_ = y[0] - mu, d1 = y[1] - mu, d2 = y[2] - mu, d3 = y[3] - mu;
    float ss = d0_ * d0_ + d1 * d1 + d2 * d2 + d3 * d3;
    ss += __shfl_xor(ss, 1); ss += __shfl_xor(ss, 2); ss += __shfl_xor(ss, 4); ss += __shfl_xor(ss, 8);
    const float rstd = 1.0f / sqrtf(ss * (1.0f / 64.0f) + 1e-5f);
    float4 gv = *(const float4*)(G + (size_t)r * D_ + d0 + tx * 4);
    float g[4] = {gv.x, gv.y, gv.z, gv.w};
#pragma unroll
    for (int j = 0; j < 4; ++j) {
      float yn = (y[j] - mu) * rstd * w4[j] + b4[j];
      float sw = g[j] / (1.0f + expf(-g[j]));
      t[tx * 4 + j][tyq + i * 16] = sw * yn;
    }
  }
  __syncthreads();
#pragma unroll
  for (int i = 0; i < 4; ++i) {
    int idx = tid + i * 256;
    int e = idx >> 4, c = (idx & 15) * 4;
    float4 v = make_float4(t[e][c], t[e][c + 1], t[e][c + 2], t[e][c + 3]);
    *(float4*)(Zt + (size_t)(d0 + e) * M_ + r0 + c) = v;
  }
}

extern "C" void kernel_launch(void* const* d_in, const int* in_sizes, int n_in,
                              void* d_out, int out_size, void* d_ws, size_t ws_size,
                              hipStream_t stream) {
  const float* X   = (const float*)d_in[0];
  const float* Wq  = (const float*)d_in[1];
  const float* Wk  = (const float*)d_in[2];
  const float* Wv  = (const float*)d_in[3];
  const float* Wg  = (const float*)d_in[4];
  const float* Wo  = (const float*)d_in[5];
  const float* gnw = (const float*)d_in[6];
  const float* gnb = (const float*)d_in[7];
  float* out = (float*)d_out;
  float* ws  = (float*)d_ws;
  const size_t NB = (size_t)M_ * D_;   // 4M floats = 16 MB
  // Buffer lifetimes (sequential kernels on one stream make the aliasing safe):
  float* b0  = ws;           // Xt (proj A)  -> Qt (rotary out)
  float* b1  = ws + NB;      // Q (proj out) -> Kt (rotary out)
  float* b2  = ws + 2 * NB;  // K (proj out) -> Y (attention out)
  float* b3  = ws + 3 * NB;  // V (proj out) -> Zt (gated norm, k-major)
  float* tab = ws + 4 * NB;  // 4 x 32768 floats xpos tables
  float* bG  = out;          // G lives in d_out until final GEMM overwrites it

  transpose_kernel<<<dim3(128, 8), 256, 0, stream>>>(X, b0);
  xpos_table_kernel<<<128, 256, 0, stream>>>(tab);
  gemm_kernel<true><<<dim3(64, 32), 256, 0, stream>>>(b0, Wq, Wk, Wv, Wg, b1, b2, b3, bG);
  rotary_kernel<<<dim3(16, 64), 256, 0, stream>>>(b1, b0, tab, 0);   // Q -> Qt (b0)
  rotary_kernel<<<dim3(16, 64), 256, 0, stream>>>(b2, b1, tab, 1);   // K -> Kt (b1)
  attn_kernel<<<dim3(16, 64), 256, 0, stream>>>(b0, b1, b3, b2);     // -> Y (b2)
  gn_gate_kernel<<<dim3(128, 8), 256, 0, stream>>>(b2, bG, gnw, gnb, b3);  // -> Zt (b3)
  gemm_kernel<false><<<dim3(64, 8), 256, 0, stream>>>(
      b3, Wo, nullptr, nullptr, nullptr, out, nullptr, nullptr, nullptr);
}

// Round 2
// 499.908 us; speedup vs baseline: 1.3645x; 1.3645x over previous
//
#include <hip/hip_runtime.h>
#include <math.h>

// MultiScaleRetention forward. B=8 S=1024 D=512 H=8 DH=64.
// This round: attention via split-bf16 MFMA (Qh+Ql)·(Kh+Kl) -> 3 mfmas, P(bf16)·(Vh+Vl).
#define B_ 8
#define S_ 1024
#define D_ 512
#define H_ 8
#define DH_ 64
#define M_ (B_*S_)   // 8192 rows

typedef __attribute__((ext_vector_type(8))) short short8;
typedef __attribute__((ext_vector_type(4))) short s16x4;
typedef __attribute__((ext_vector_type(4))) float f32x4;

__device__ inline unsigned short bf16h(float x) {
  unsigned u = __float_as_uint(x);
  return (unsigned short)((u + 0x7FFFu + ((u >> 16) & 1u)) >> 16);   // RNE
}
__device__ inline float bf16tof(unsigned short h) { return __uint_as_float(((unsigned)h) << 16); }

__device__ inline f32x4 mfma16(short8 a, short8 b, f32x4 c) {
  return __builtin_amdgcn_mfma_f32_16x16x32_bf16(a, b, c, 0, 0, 0);
}

// ---------- X [M,512] -> Xt [512,M] ----------
__global__ __launch_bounds__(256) void transpose_kernel(const float* __restrict__ X,
                                                        float* __restrict__ Xt) {
  __shared__ float t[64][65];
  const int m0 = blockIdx.x * 64, d0 = blockIdx.y * 64;
  const int tid = threadIdx.x;
#pragma unroll
  for (int i = 0; i < 4; ++i) {
    int idx = tid + i * 256;
    int r = idx >> 4, c = (idx & 15) * 4;
    float4 v = *(const float4*)(X + (size_t)(m0 + r) * D_ + d0 + c);
    t[r][c] = v.x; t[r][c+1] = v.y; t[r][c+2] = v.z; t[r][c+3] = v.w;
  }
  __syncthreads();
#pragma unroll
  for (int i = 0; i < 4; ++i) {
    int idx = tid + i * 256;
    int r = idx >> 4, c = (idx & 15) * 4;
    float4 v = make_float4(t[c][r], t[c+1][r], t[c+2][r], t[c+3][r]);
    *(float4*)(Xt + (size_t)(d0 + r) * M_ + m0 + c) = v;
  }
}

// ---------- xpos tables: 4 x [1024][32] = cosQ | sinQ | cosK | sinK ----------
__global__ void xpos_table_kernel(float* __restrict__ tab) {
  int idx = blockIdx.x * 256 + threadIdx.x;
  int s = idx >> 5, i = idx & 31;
  float sv = (2.0f * (float)i + 0.4f * 64.0f) / (1.4f * 64.0f);
  float p = (float)s / 512.0f;
  float scale = powf(sv, p);
  float inv_freq = powf(10000.0f, -((float)i / 32.0f));
  float ang = (float)s * inv_freq;
  float sn = sinf(ang), cs = cosf(ang);
  tab[idx]          = cs * scale;
  tab[32768 + idx]  = sn * scale;
  tab[65536 + idx]  = cs / scale;
  tab[98304 + idx]  = sn / scale;
}

// ---------- GEMM: C = At^T * B.  At k-major [512][8192]. 128x64 tile, 8x4 micro ----------
template<bool FUSED>
__global__ __launch_bounds__(256) void gemm_kernel(
    const float* __restrict__ At,
    const float* __restrict__ W0, const float* __restrict__ W1,
    const float* __restrict__ W2, const float* __restrict__ W3,
    float* __restrict__ O0, float* __restrict__ O1,
    float* __restrict__ O2, float* __restrict__ O3) {
  __shared__ float As[16][128];
  __shared__ float Bs[16][64];
  const int m0 = blockIdx.x * 128;
  const int n0g = blockIdx.y * 64;
  const float* Bp;
  float* Cp;
  int ldb, cmode = 0, h = 0, ncol = 0;
  if constexpr (FUSED) {
    int w = n0g >> 9, n0 = n0g & 511;
    const float* Ws[4] = {W0, W1, W2, W3};
    float* Os[4] = {O0, O1, O2, O3};
    Cp = Os[w];
    if (w < 3) { h = n0 >> 6; Bp = Ws[w] + (size_t)h * D_ * DH_; ldb = DH_; cmode = 1; }
    else       { Bp = W3 + n0; ldb = D_; cmode = 0; ncol = n0; }
  } else {
    Bp = W0 + n0g; ldb = D_; Cp = O0; ncol = n0g;
  }
  const int tid = threadIdx.x, tx = tid & 15, ty = tid >> 4;
  float acc[8][4] = {};
  for (int k0 = 0; k0 < D_; k0 += 16) {
#pragma unroll
    for (int i = 0; i < 2; ++i) {
      int idx = tid + i * 256;
      int kk = idx >> 5, mm = (idx & 31) * 4;
      *(float4*)&As[kk][mm] = *(const float4*)(At + (size_t)(k0 + kk) * M_ + m0 + mm);
    }
    {
      int kk = tid >> 4, nn = (tid & 15) * 4;
      *(float4*)&Bs[kk][nn] = *(const float4*)(Bp + (size_t)(k0 + kk) * ldb + nn);
    }
    __syncthreads();
#pragma unroll
    for (int kk = 0; kk < 16; ++kk) {
      float4 a0 = *(const float4*)&As[kk][ty * 8];
      float4 a1 = *(const float4*)&As[kk][ty * 8 + 4];
      float4 b4 = *(const float4*)&Bs[kk][tx * 4];
      float ar[8] = {a0.x, a0.y, a0.z, a0.w, a1.x, a1.y, a1.z, a1.w};
      float br[4] = {b4.x, b4.y, b4.z, b4.w};
#pragma unroll
      for (int i = 0; i < 8; ++i)
#pragma unroll
        for (int j = 0; j < 4; ++j) acc[i][j] += ar[i] * br[j];
    }
    __syncthreads();
  }
#pragma unroll
  for (int i = 0; i < 8; ++i) {
    int r = m0 + ty * 8 + i;
    float4 v = make_float4(acc[i][0], acc[i][1], acc[i][2], acc[i][3]);
    size_t addr;
    if (cmode == 1) {
      int bb = r >> 10, s = r & 1023;
      addr = (((size_t)(bb * H_ + h)) * S_ + s) * DH_ + tx * 4;
    } else {
      addr = (size_t)r * D_ + ncol + tx * 4;
    }
    *(float4*)(Cp + addr) = v;
  }
}

// ---------- xpos rotary, elementwise (layout [bh][s][64] preserved) ----------
__global__ __launch_bounds__(256) void rotary_ew_kernel(const float* __restrict__ in,
                                                        float* __restrict__ outp,
                                                        const float* __restrict__ tab, int isK) {
  int idx = blockIdx.x * 256 + threadIdx.x;          // 1M threads x float4
  size_t base = (size_t)idx * 4;
  int e4 = (int)(base & 63);
  int s = (int)((base >> 6) & (S_ - 1));
  const float* ct = tab + (isK ? 65536 : 0) + s * 32;
  const float* st = tab + (isK ? 98304 : 32768) + s * 32;
  float4 v = *(const float4*)(in + base);
  int i0 = e4 >> 1;
  float c0 = ct[i0], s0v = st[i0], c1 = ct[i0 + 1], s1v = st[i0 + 1];
  float4 o;
  o.x = v.x * c0 - v.y * s0v;
  o.y = v.y * c0 + v.x * s0v;
  o.z = v.z * c1 - v.w * s1v;
  o.w = v.w * c1 + v.z * s1v;
  *(float4*)(outp + base) = o;
}

// ---------- V [bh][s][64] -> Vt [bh][64][S] ----------
__global__ __launch_bounds__(256) void vtrans_kernel(const float* __restrict__ V,
                                                     float* __restrict__ Vt) {
  __shared__ float t[64][65];
  const int s0 = blockIdx.x * 64, bh = blockIdx.y;
  const int tid = threadIdx.x;
  const float* src = V + (size_t)bh * S_ * DH_;
  float* dst = Vt + (size_t)bh * DH_ * S_;
#pragma unroll
  for (int i = 0; i < 4; ++i) {
    int idx = tid + i * 256;
    int r = idx >> 4, c = (idx & 15) * 4;            // r: s-local, c: e
    float4 v = *(const float4*)(src + (size_t)(s0 + r) * DH_ + c);
    t[r][c] = v.x; t[r][c+1] = v.y; t[r][c+2] = v.z; t[r][c+3] = v.w;
  }
  __syncthreads();
#pragma unroll
  for (int i = 0; i < 4; ++i) {
    int idx = tid + i * 256;
    int e = idx >> 4, c = (idx & 15) * 4;            // e row, c: s-local
    float4 v = make_float4(t[c][e], t[c+1][e], t[c+2][e], t[c+3][e]);
    *(float4*)(dst + (size_t)e * S_ + s0 + c) = v;
  }
}

// ---------- attention: split-bf16 MFMA, online softmax * decay ----------
// Block: 4 waves, 128 s-rows (32/wave), t-tiles of 64.
// mfma_f32_16x16x32_bf16 layouts (HW-verified): A[m=lane&15][k=(lane>>4)*8+j],
// B[n=lane&15][k=(lane>>4)*8+j], D row=(lane>>4)*4+reg, col=lane&15.
__global__ __launch_bounds__(256, 2) void attn_mfma_kernel(const float* __restrict__ Q,
                                                           const float* __restrict__ K,
                                                           const float* __restrict__ Vt,
                                                           float* __restrict__ Y) {
  __shared__ __align__(16) short KhS[64][72];   // [t][e], +8 pad for b128 bank spread
  __shared__ __align__(16) short KlS[64][72];
  __shared__ __align__(16) short VhS[64][72];   // [e][t]
  __shared__ __align__(16) short VlS[64][72];
  __shared__ __align__(16) short PhS[4][32][72];  // per-wave [s][t], bf16 of decayed P
  const int s0 = blockIdx.x * 128, bh = blockIdx.y;
  const int b = bh >> 3, h = bh & 7;
  const int tid = threadIdx.x;
  const int w = tid >> 6, lane = tid & 63;
  const int lx = lane & 15, quad = lane >> 4;
  const float l0c = -3.4657359027997265f;   // ln(1/32)
  const float l1c = -6.2383246250395075f;   // ln(1/512)
  const float gamma = 1.0f - expf(l0c + (float)h * (l1c - l0c) / 7.0f);
  const float lg2g = log2f(gamma);
  const float* Qb = Q + (size_t)bh * S_ * DH_;
  const float* Kb = K + (size_t)bh * S_ * DH_;
  const float* Vb = Vt + (size_t)bh * DH_ * S_;

  // Q A-fragments, split hi/lo: [msub][kchunk]
  short8 qh[2][2], ql[2][2];
#pragma unroll
  for (int ms = 0; ms < 2; ++ms)
#pragma unroll
    for (int kc = 0; kc < 2; ++kc) {
      const float* qp = Qb + (size_t)(s0 + w * 32 + ms * 16 + lx) * DH_ + kc * 32 + quad * 8;
      float4 a = *(const float4*)qp, c = *(const float4*)(qp + 4);
      float xs[8] = {a.x, a.y, a.z, a.w, c.x, c.y, c.z, c.w};
      short8 hh, ll;
#pragma unroll
      for (int j = 0; j < 8; ++j) {
        unsigned short hb = bf16h(xs[j]);
        hh[j] = (short)hb;
        ll[j] = (short)bf16h(xs[j] - bf16tof(hb));
      }
      qh[ms][kc] = hh; ql[ms][kc] = ll;
    }

  f32x4 O[2][4] = {};          // [msub][nsub(e)], C-layout rows
  float m_r[2][4], l_r[2][4];
#pragma unroll
  for (int ms = 0; ms < 2; ++ms)
#pragma unroll
    for (int rg = 0; rg < 4; ++rg) { m_r[ms][rg] = -1e30f; l_r[ms][rg] = 0.0f; }

  for (int t0 = 0; t0 < S_; t0 += 64) {
    __syncthreads();   // prior tile's K/V reads complete before restage
    // ---- stage K (split) and V (split) tiles ----
#pragma unroll
    for (int i = 0; i < 4; ++i) {
      int r = (tid >> 4) + i * 16, c4 = (tid & 15) * 4;
      float4 kv = *(const float4*)(Kb + (size_t)(t0 + r) * DH_ + c4);
      float ks[4] = {kv.x, kv.y, kv.z, kv.w};
      s16x4 h4, l4;
#pragma unroll
      for (int j = 0; j < 4; ++j) {
        unsigned short hb = bf16h(ks[j]);
        h4[j] = (short)hb;
        l4[j] = (short)bf16h(ks[j] - bf16tof(hb));
      }
      *(s16x4*)&KhS[r][c4] = h4; *(s16x4*)&KlS[r][c4] = l4;
      float4 vv = *(const float4*)(Vb + (size_t)r * S_ + t0 + c4);
      float vs[4] = {vv.x, vv.y, vv.z, vv.w};
#pragma unroll
      for (int j = 0; j < 4; ++j) {
        unsigned short hb = bf16h(vs[j]);
        h4[j] = (short)hb;
        l4[j] = (short)bf16h(vs[j] - bf16tof(hb));
      }
      *(s16x4*)&VhS[r][c4] = h4; *(s16x4*)&VlS[r][c4] = l4;
    }
    __syncthreads();
    // ---- QK^T: S = Qh·Kh + Ql·Kh + Qh·Kl ----
    f32x4 acc[2][4];
#pragma unroll
    for (int ns = 0; ns < 4; ++ns) {
      short8 kh0 = *(const short8*)&KhS[ns * 16 + lx][quad * 8];
      short8 kh1 = *(const short8*)&KhS[ns * 16 + lx][32 + quad * 8];
      short8 kl0 = *(const short8*)&KlS[ns * 16 + lx][quad * 8];
      short8 kl1 = *(const short8*)&KlS[ns * 16 + lx][32 + quad * 8];
#pragma unroll
      for (int ms = 0; ms < 2; ++ms) {
        f32x4 a = {};
        a = mfma16(qh[ms][0], kh0, a);
        a = mfma16(ql[ms][0], kh0, a);
        a = mfma16(qh[ms][0], kl0, a);
        a = mfma16(qh[ms][1], kh1, a);
        a = mfma16(ql[ms][1], kh1, a);
        a = mfma16(qh[ms][1], kl1, a);
        acc[ms][ns] = a;
      }
    }
    // ---- online softmax (undecayed denominator), decay into P, write bf16 P ----
#pragma unroll
    for (int ms = 0; ms < 2; ++ms)
#pragma unroll
      for (int rg = 0; rg < 4; ++rg) {
        float v = fmaxf(fmaxf(acc[ms][0][rg], acc[ms][1][rg]),
                        fmaxf(acc[ms][2][rg], acc[ms][3][rg]));
        v = fmaxf(v, __shfl_xor(v, 1));
        v = fmaxf(v, __shfl_xor(v, 2));
        v = fmaxf(v, __shfl_xor(v, 4));
        v = fmaxf(v, __shfl_xor(v, 8));
        const float mnew = fmaxf(m_r[ms][rg], v);
        const float alpha = expf(m_r[ms][rg] - mnew);
        float p[4], rs = 0.0f;
#pragma unroll
        for (int ns = 0; ns < 4; ++ns) { p[ns] = expf(acc[ms][ns][rg] - mnew); rs += p[ns]; }
        rs += __shfl_xor(rs, 1);
        rs += __shfl_xor(rs, 2);
        rs += __shfl_xor(rs, 4);
        rs += __shfl_xor(rs, 8);
        l_r[ms][rg] = l_r[ms][rg] * alpha + rs;
        m_r[ms][rg] = mnew;
        const int rloc = ms * 16 + quad * 4 + rg;
        const int srow = s0 + w * 32 + rloc;
#pragma unroll
        for (int ns = 0; ns < 4; ++ns) {
          O[ms][ns][rg] *= alpha;
          float dd = exp2f(lg2g * fabsf((float)(srow - (t0 + ns * 16 + lx))));
          PhS[w][rloc][ns * 16 + lx] = (short)bf16h(p[ns] * dd);
        }
      }
    // ---- PV: O += P·(Vh+Vl); P A-frags from per-wave LDS (same-wave, no barrier) ----
    short8 pf[2][2];
#pragma unroll
    for (int ms = 0; ms < 2; ++ms)
#pragma unroll
      for (int kc = 0; kc < 2; ++kc)
        pf[ms][kc] = *(const short8*)&PhS[w][ms * 16 + lx][kc * 32 + quad * 8];
#pragma unroll
    for (int ns = 0; ns < 4; ++ns) {
      short8 vh0 = *(const short8*)&VhS[ns * 16 + lx][quad * 8];
      short8 vh1 = *(const short8*)&VhS[ns * 16 + lx][32 + quad * 8];
      short8 vl0 = *(const short8*)&VlS[ns * 16 + lx][quad * 8];
      short8 vl1 = *(const short8*)&VlS[ns * 16 + lx][32 + quad * 8];
#pragma unroll
      for (int ms = 0; ms < 2; ++ms) {
        f32x4 o = O[ms][ns];
        o = mfma16(pf[ms][0], vh0, o);
        o = mfma16(pf[ms][0], vl0, o);
        o = mfma16(pf[ms][1], vh1, o);
        o = mfma16(pf[ms][1], vl1, o);
        O[ms][ns] = o;
      }
    }
  }
  // ---- epilogue: O / l -> Y [b][s][h*64+e] ----
#pragma unroll
  for (int ms = 0; ms < 2; ++ms)
#pragma unroll
    for (int rg = 0; rg < 4; ++rg) {
      const float inv = 1.0f / l_r[ms][rg];
      const int srow = s0 + w * 32 + ms * 16 + quad * 4 + rg;
#pragma unroll
      for (int ns = 0; ns < 4; ++ns) {
        Y[((size_t)(b * S_ + srow)) * D_ + h * DH_ + ns * 16 + lx] = O[ms][ns][rg] * inv;
      }
    }
}

// ---------- GroupNorm + swish(G) gate + transpose -> Zt [512][8192] ----------
__global__ __launch_bounds__(256) void gn_gate_kernel(const float* __restrict__ Y,
                                                      const float* __restrict__ G,
                                                      const float* __restrict__ gnw,
                                                      const float* __restrict__ gnb,
                                                      float* __restrict__ Zt) {
  __shared__ float t[64][65];
  const int r0 = blockIdx.x * 64, h = blockIdx.y, d0 = h * DH_;
  const int tid = threadIdx.x, tx = tid & 15, tyq = tid >> 4;
  float4 wv = *(const float4*)(gnw + d0 + tx * 4);
  float4 bv = *(const float4*)(gnb + d0 + tx * 4);
  float w4[4] = {wv.x, wv.y, wv.z, wv.w};
  float b4[4] = {bv.x, bv.y, bv.z, bv.w};
#pragma unroll
  for (int i = 0; i < 4; ++i) {
    int r = r0 + tyq + i * 16;
    float4 yv = *(const float4*)(Y + (size_t)r * D_ + d0 + tx * 4);
    float y[4] = {yv.x, yv.y, yv.z, yv.w};
    float s = y[0] + y[1] + y[2] + y[3];
    s += __shfl_xor(s, 1); s += __shfl_xor(s, 2); s += __shfl_xor(s, 4); s += __shfl_xor(s, 8);
    const float mu = s * (1.0f / 64.0f);
    float d0_ = y[0] - mu, d1 = y[1] - mu, d2 = y[2] - mu, d3 = y[3] - mu;
    float ss = d0_ * d0_ + d1 * d1 + d2 * d2 + d3 * d3;
    ss += __shfl_xor(ss, 1); ss += __shfl_xor(ss, 2); ss += __shfl_xor(ss, 4); ss += __shfl_xor(ss, 8);
    const float rstd = 1.0f / sqrtf(ss * (1.0f / 64.0f) + 1e-5f);
    float4 gv = *(const float4*)(G + (size_t)r * D_ + d0 + tx * 4);
    float g[4] = {gv.x, gv.y, gv.z, gv.w};
#pragma unroll
    for (int j = 0; j < 4; ++j) {
      float yn = (y[j] - mu) * rstd * w4[j] + b4[j];
      float sw = g[j] / (1.0f + expf(-g[j]));
      t[tx * 4 + j][tyq + i * 16] = sw * yn;
    }
  }
  __syncthreads();
#pragma unroll
  for (int i = 0; i < 4; ++i) {
    int idx = tid + i * 256;
    int e = idx >> 4, c = (idx & 15) * 4;
    float4 v = make_float4(t[e][c], t[e][c + 1], t[e][c + 2], t[e][c + 3]);
    *(float4*)(Zt + (size_t)(d0 + e) * M_ + r0 + c) = v;
  }
}

extern "C" void kernel_launch(void* const* d_in, const int* in_sizes, int n_in,
                              void* d_out, int out_size, void* d_ws, size_t ws_size,
                              hipStream_t stream) {
  const float* X   = (const float*)d_in[0];
  const float* Wq  = (const float*)d_in[1];
  const float* Wk  = (const float*)d_in[2];
  const float* Wv  = (const float*)d_in[3];
  const float* Wg  = (const float*)d_in[4];
  const float* Wo  = (const float*)d_in[5];
  const float* gnw = (const float*)d_in[6];
  const float* gnb = (const float*)d_in[7];
  float* out = (float*)d_out;
  float* ws  = (float*)d_ws;
  const size_t NB = (size_t)M_ * D_;   // 16 MB each
  // Buffer lifetimes (kernels are stream-ordered):
  // b0: Xt -> Qr -> Zt;  b1: Q -> Kr;  b2: K -> Vt;  b3: V -> Y;  out: G -> final
  float* b0  = ws;
  float* b1  = ws + NB;
  float* b2  = ws + 2 * NB;
  float* b3  = ws + 3 * NB;
  float* tab = ws + 4 * NB;
  float* bG  = out;

  transpose_kernel<<<dim3(128, 8), 256, 0, stream>>>(X, b0);
  xpos_table_kernel<<<128, 256, 0, stream>>>(tab);
  gemm_kernel<true><<<dim3(64, 32), 256, 0, stream>>>(b0, Wq, Wk, Wv, Wg, b1, b2, b3, bG);
  rotary_ew_kernel<<<4096, 256, 0, stream>>>(b1, b0, tab, 0);   // Q -> Qr (b0)
  rotary_ew_kernel<<<4096, 256, 0, stream>>>(b2, b1, tab, 1);   // K -> Kr (b1)
  vtrans_kernel<<<dim3(16, 64), 256, 0, stream>>>(b3, b2);      // V -> Vt (b2)
  attn_mfma_kernel<<<dim3(8, 64), 256, 0, stream>>>(b0, b1, b2, b3);   // -> Y (b3)
  gn_gate_kernel<<<dim3(128, 8), 256, 0, stream>>>(b3, bG, gnw, gnb, b0);  // -> Zt (b0)
  gemm_kernel<false><<<dim3(64, 8), 256, 0, stream>>>(
      b0, Wo, nullptr, nullptr, nullptr, out, nullptr, nullptr, nullptr);
}

// Round 3
// 257.320 us; speedup vs baseline: 2.6509x; 1.9427x over previous
//
#include <hip/hip_runtime.h>
#include <math.h>

// MultiScaleRetention forward. B=8 S=1024 D=512 H=8 DH=64.
// R3: split-bf16 MFMA for both GEMMs (3 mfma per fp32 product, trunc-split),
//     attention softmax diet (no max-tracking, deferred l-reduce, factored decay),
//     V^T emitted split-bf16 straight from the projection GEMM epilogue.
#define B_ 8
#define S_ 1024
#define D_ 512
#define H_ 8
#define DH_ 64
#define M_ (B_*S_)   // 8192 rows

typedef __attribute__((ext_vector_type(8))) short short8;
typedef __attribute__((ext_vector_type(4))) short s16x4;
typedef __attribute__((ext_vector_type(4))) float f32x4;

// RNE bf16 (used for P only)
__device__ inline unsigned short bf16h(float x) {
  unsigned u = __float_as_uint(x);
  return (unsigned short)((u + 0x7FFFu + ((u >> 16) & 1u)) >> 16);
}
// trunc split: x = hi + lo + O(2^-16 |x|); x - hi is exact in fp32.
__device__ inline void tsplit(float x, short& hs, short& ls) {
  unsigned u = __float_as_uint(x);
  hs = (short)(u >> 16);
  float r = x - __uint_as_float(u & 0xFFFF0000u);
  ls = (short)(__float_as_uint(r) >> 16);
}
__device__ inline f32x4 mfma16(short8 a, short8 b, f32x4 c) {
  return __builtin_amdgcn_mfma_f32_16x16x32_bf16(a, b, c, 0, 0, 0);
}

// ---------- xpos tables: 4 x [1024][32] = cosQ | sinQ | cosK | sinK ----------
__global__ void xpos_table_kernel(float* __restrict__ tab) {
  int idx = blockIdx.x * 256 + threadIdx.x;
  int s = idx >> 5, i = idx & 31;
  float sv = (2.0f * (float)i + 0.4f * 64.0f) / (1.4f * 64.0f);
  float p = (float)s / 512.0f;
  float scale = powf(sv, p);
  float inv_freq = powf(10000.0f, -((float)i / 32.0f));
  float ang = (float)s * inv_freq;
  float sn = sinf(ang), cs = cosf(ang);
  tab[idx]          = cs * scale;
  tab[32768 + idx]  = sn * scale;
  tab[65536 + idx]  = cs / scale;
  tab[98304 + idx]  = sn / scale;
}

// ---------- weight prep: BT[n][k] split bf16 from W ----------
// fused (gonly=0): n 0..2047 spans W_Q | W_K | W_V (each [h][k][e]) | W_G [k][n].
// gonly=1: Wg-style matrix only (used for W_O), n 0..511.
__global__ __launch_bounds__(256) void wprep_kernel(
    const float* __restrict__ Wq, const float* __restrict__ Wk,
    const float* __restrict__ Wv, const float* __restrict__ Wg,
    short* __restrict__ BTh, short* __restrict__ BTl, int gonly) {
  __shared__ float t[64][65];
  const int n0 = blockIdx.x * 64, k0 = blockIdx.y * 64;
  const int tid = threadIdx.x;
  const float* src;
  int ld;
  if (gonly) {
    src = Wg + (size_t)k0 * 512 + n0; ld = 512;
  } else {
    int w = n0 >> 9, nn = n0 & 511;
    if (w == 3) { src = Wg + (size_t)k0 * 512 + nn; ld = 512; }
    else {
      const float* W = (w == 0) ? Wq : ((w == 1) ? Wk : Wv);
      int h = nn >> 6;
      src = W + (size_t)h * D_ * DH_ + (size_t)k0 * 64; ld = 64;
    }
  }
#pragma unroll
  for (int i = 0; i < 4; ++i) {
    int idx = tid + i * 256;
    int kk = idx >> 4, nl4 = (idx & 15) * 4;
    float4 v = *(const float4*)(src + (size_t)kk * ld + nl4);
    t[kk][nl4] = v.x; t[kk][nl4 + 1] = v.y; t[kk][nl4 + 2] = v.z; t[kk][nl4 + 3] = v.w;
  }
  __syncthreads();
#pragma unroll
  for (int i = 0; i < 2; ++i) {
    int idx = tid + i * 256;
    int nl = idx >> 3, ck = idx & 7;
    short8 hh, ll;
#pragma unroll
    for (int j = 0; j < 8; ++j) {
      short h_, l_;
      tsplit(t[ck * 8 + j][nl], h_, l_);
      hh[j] = h_; ll[j] = l_;
    }
    size_t off = (size_t)(n0 + nl) * 512 + k0 + ck * 8;
    *(short8*)(BTh + off) = hh;
    *(short8*)(BTl + off) = ll;
  }
}

// ---------- split-bf16 MFMA GEMM: C = A * BT^T. 128x128 tile, BK=32 ----------
// A: fp32 [M][512] (inline trunc-split) or pre-split bf16 Ah/Al [M][512].
// fused epilogue: by 0..15 -> Q fp32 [b,h,s,e] | K fp32 | V^T split bf16 [bh][e][s] | G fp32 [m][512].
// !fused: out fp32 [m][512] (G ptr).
template<bool PRESPLIT>
__global__ __launch_bounds__(256) void gemm_mfma_kernel(
    const float* __restrict__ Af,
    const short* __restrict__ Ah, const short* __restrict__ Al,
    const short* __restrict__ BTh, const short* __restrict__ BTl,
    float* __restrict__ Qo, float* __restrict__ Ko,
    short* __restrict__ VhT, short* __restrict__ VlT,
    float* __restrict__ G, int fused) {
  __shared__ __align__(16) short AsH[128][40];   // 32 k + 8 pad (80B rows: 2-way = free)
  __shared__ __align__(16) short AsL[128][40];
  __shared__ __align__(16) short BsH[128][40];
  __shared__ __align__(16) short BsL[128][40];
  const int m0 = blockIdx.x * 128, by = blockIdx.y, n0 = by * 128;
  const int tid = threadIdx.x, w = tid >> 6, lane = tid & 63;
  const int lx = lane & 15, quad = lane >> 4;
  const int wr = w >> 1, wc = w & 1;
  f32x4 acc[4][4] = {};
  for (int k0 = 0; k0 < 512; k0 += 32) {
    if constexpr (PRESPLIT) {
#pragma unroll
      for (int i = 0; i < 2; ++i) {
        int idx = tid + i * 256;
        int r = idx >> 2, sg = (idx & 3) * 8;
        *(short8*)&AsH[r][sg] = *(const short8*)(Ah + (size_t)(m0 + r) * 512 + k0 + sg);
        *(short8*)&AsL[r][sg] = *(const short8*)(Al + (size_t)(m0 + r) * 512 + k0 + sg);
      }
    } else {
      int r = tid >> 1, kh = (tid & 1) * 16;
      const float* ap = Af + (size_t)(m0 + r) * 512 + k0 + kh;
#pragma unroll
      for (int j4 = 0; j4 < 4; ++j4) {
        float4 v = *(const float4*)(ap + j4 * 4);
        s16x4 hh, ll;
        short h_, l_;
        tsplit(v.x, h_, l_); hh[0] = h_; ll[0] = l_;
        tsplit(v.y, h_, l_); hh[1] = h_; ll[1] = l_;
        tsplit(v.z, h_, l_); hh[2] = h_; ll[2] = l_;
        tsplit(v.w, h_, l_); hh[3] = h_; ll[3] = l_;
        *(s16x4*)&AsH[r][kh + j4 * 4] = hh;
        *(s16x4*)&AsL[r][kh + j4 * 4] = ll;
      }
    }
#pragma unroll
    for (int i = 0; i < 2; ++i) {
      int idx = tid + i * 256;
      int r = idx >> 2, sg = (idx & 3) * 8;
      *(short8*)&BsH[r][sg] = *(const short8*)(BTh + (size_t)(n0 + r) * 512 + k0 + sg);
      *(short8*)&BsL[r][sg] = *(const short8*)(BTl + (size_t)(n0 + r) * 512 + k0 + sg);
    }
    __syncthreads();
    short8 fah[4], fal[4], fbh[4], fbl[4];
#pragma unroll
    for (int i = 0; i < 4; ++i) {
      fah[i] = *(const short8*)&AsH[wr * 64 + i * 16 + lx][quad * 8];
      fal[i] = *(const short8*)&AsL[wr * 64 + i * 16 + lx][quad * 8];
      fbh[i] = *(const short8*)&BsH[wc * 64 + i * 16 + lx][quad * 8];
      fbl[i] = *(const short8*)&BsL[wc * 64 + i * 16 + lx][quad * 8];
    }
#pragma unroll
    for (int ms = 0; ms < 4; ++ms)
#pragma unroll
      for (int ns = 0; ns < 4; ++ns) {
        f32x4 a = acc[ms][ns];
        a = mfma16(fah[ms], fbh[ns], a);
        a = mfma16(fal[ms], fbh[ns], a);
        a = mfma16(fah[ms], fbl[ns], a);
        acc[ms][ns] = a;
      }
    __syncthreads();
  }
  // ---- epilogue ----
  if (fused) {
    const int w4 = by >> 2;
    const int ncb = (by & 3) * 128 + wc * 64;   // within 512
    if (w4 < 2) {
      float* P = (w4 == 0) ? Qo : Ko;
#pragma unroll
      for (int ms = 0; ms < 4; ++ms) {
        const int m = m0 + wr * 64 + ms * 16 + quad * 4;
        const int b = m >> 10, s = m & 1023;
#pragma unroll
        for (int ns = 0; ns < 4; ++ns) {
          const int n = ncb + ns * 16 + lx;
          const int h = n >> 6, e = n & 63;
          float* bp = P + (((size_t)(b * 8 + h)) * 1024 + s) * 64 + e;
#pragma unroll
          for (int rg = 0; rg < 4; ++rg) bp[rg * 64] = acc[ms][ns][rg];
        }
      }
    } else if (w4 == 2) {
#pragma unroll
      for (int ms = 0; ms < 4; ++ms) {
        const int m = m0 + wr * 64 + ms * 16 + quad * 4;
        const int b = m >> 10, s = m & 1023;
#pragma unroll
        for (int ns = 0; ns < 4; ++ns) {
          const int n = ncb + ns * 16 + lx;
          const int h = n >> 6, e = n & 63;
          s16x4 hh, ll;
#pragma unroll
          for (int rg = 0; rg < 4; ++rg) {
            short h_, l_;
            tsplit(acc[ms][ns][rg], h_, l_);
            hh[rg] = h_; ll[rg] = l_;
          }
          size_t off = (((size_t)(b * 8 + h)) * 64 + e) * 1024 + s;
          *(s16x4*)(VhT + off) = hh;
          *(s16x4*)(VlT + off) = ll;
        }
      }
    } else {
#pragma unroll
      for (int ms = 0; ms < 4; ++ms) {
        const int m = m0 + wr * 64 + ms * 16 + quad * 4;
#pragma unroll
        for (int ns = 0; ns < 4; ++ns) {
          const int n = ncb + ns * 16 + lx;
#pragma unroll
          for (int rg = 0; rg < 4; ++rg) G[(size_t)(m + rg) * 512 + n] = acc[ms][ns][rg];
        }
      }
    }
  } else {
#pragma unroll
    for (int ms = 0; ms < 4; ++ms) {
      const int m = m0 + wr * 64 + ms * 16 + quad * 4;
#pragma unroll
      for (int ns = 0; ns < 4; ++ns) {
        const int n = n0 + wc * 64 + ns * 16 + lx;
#pragma unroll
        for (int rg = 0; rg < 4; ++rg) G[(size_t)(m + rg) * 512 + n] = acc[ms][ns][rg];
      }
    }
  }
}

// ---------- xpos rotary, elementwise fp32 [bh][s][64] ----------
__global__ __launch_bounds__(256) void rotary_ew_kernel(const float* __restrict__ in,
                                                        float* __restrict__ outp,
                                                        const float* __restrict__ tab, int isK) {
  int idx = blockIdx.x * 256 + threadIdx.x;
  size_t base = (size_t)idx * 4;
  int e4 = (int)(base & 63);
  int s = (int)((base >> 6) & (S_ - 1));
  const float* ct = tab + (isK ? 65536 : 0) + s * 32;
  const float* st = tab + (isK ? 98304 : 32768) + s * 32;
  float4 v = *(const float4*)(in + base);
  int i0 = e4 >> 1;
  float c0 = ct[i0], s0v = st[i0], c1 = ct[i0 + 1], s1v = st[i0 + 1];
  float4 o;
  o.x = v.x * c0 - v.y * s0v;
  o.y = v.y * c0 + v.x * s0v;
  o.z = v.z * c1 - v.w * s1v;
  o.w = v.w * c1 + v.z * s1v;
  *(float4*)(outp + base) = o;
}

// ---------- attention: split-bf16 MFMA, one-pass softmax (bounded scores), factored decay ----
__global__ __launch_bounds__(256, 2) void attn_mfma_kernel(const float* __restrict__ Q,
                                                           const float* __restrict__ K,
                                                           const short* __restrict__ VhT,
                                                           const short* __restrict__ VlT,
                                                           float* __restrict__ Y) {
  __shared__ __align__(16) short KhS[64][72];     // [t][e]
  __shared__ __align__(16) short KlS[64][72];
  __shared__ __align__(16) short VhS[64][72];     // [e][t]
  __shared__ __align__(16) short VlS[64][72];
  __shared__ __align__(16) short PhS[4][32][72];  // per-wave [s][t]
  const int s0 = blockIdx.x * 128, bh = blockIdx.y;
  const int b = bh >> 3, h = bh & 7;
  const int tid = threadIdx.x;
  const int w = tid >> 6, lane = tid & 63;
  const int lx = lane & 15, quad = lane >> 4;
  const int s0w = s0 + w * 32;
  const float l0c = -3.4657359027997265f;   // ln(1/32)
  const float l1c = -6.2383246250395075f;   // ln(1/512)
  const float gamma = 1.0f - expf(l0c + (float)h * (l1c - l0c) / 7.0f);
  const float lg2g = log2f(gamma);
  const float* Qb = Q + (size_t)bh * S_ * DH_;
  const float* Kb = K + (size_t)bh * S_ * DH_;
  const short* VbH = VhT + (size_t)bh * DH_ * S_;
  const short* VbL = VlT + (size_t)bh * DH_ * S_;

  // decay column factors (per lane, per ns)
  float cl[4], cr[4];
#pragma unroll
  for (int ns = 0; ns < 4; ++ns) {
    cl[ns] = exp2f(lg2g * (float)(ns * 16 + lx));
    cr[ns] = exp2f(lg2g * (float)(63 - ns * 16 - lx));
  }

  // Q A-fragments, trunc-split hi/lo: [msub][kchunk]
  short8 qh[2][2], ql[2][2];
#pragma unroll
  for (int ms = 0; ms < 2; ++ms)
#pragma unroll
    for (int kc = 0; kc < 2; ++kc) {
      const float* qp = Qb + (size_t)(s0w + ms * 16 + lx) * DH_ + kc * 32 + quad * 8;
      float4 a = *(const float4*)qp, c = *(const float4*)(qp + 4);
      float xs[8] = {a.x, a.y, a.z, a.w, c.x, c.y, c.z, c.w};
      short8 hh, ll;
#pragma unroll
      for (int j = 0; j < 8; ++j) {
        short h_, l_;
        tsplit(xs[j], h_, l_);
        hh[j] = h_; ll[j] = l_;
      }
      qh[ms][kc] = hh; ql[ms][kc] = ll;
    }

  f32x4 O[2][4] = {};
  float lsum[2][4] = {};

  for (int t0 = 0; t0 < S_; t0 += 64) {
    __syncthreads();   // prior tile's K/V reads complete before restage
    // ---- stage K (fp32 -> trunc-split) and V (pre-split copy) ----
#pragma unroll
    for (int i = 0; i < 4; ++i) {
      int r = (tid >> 4) + i * 16, c4 = (tid & 15) * 4;
      float4 kv = *(const float4*)(Kb + (size_t)(t0 + r) * DH_ + c4);
      float ks[4] = {kv.x, kv.y, kv.z, kv.w};
      s16x4 h4, l4;
#pragma unroll
      for (int j = 0; j < 4; ++j) {
        short h_, l_;
        tsplit(ks[j], h_, l_);
        h4[j] = h_; l4[j] = l_;
      }
      *(s16x4*)&KhS[r][c4] = h4;
      *(s16x4*)&KlS[r][c4] = l4;
    }
#pragma unroll
    for (int i = 0; i < 2; ++i) {
      int idx = tid + i * 256;
      int e = idx >> 3, c8 = (idx & 7) * 8;
      *(short8*)&VhS[e][c8] = *(const short8*)(VbH + (size_t)e * S_ + t0 + c8);
      *(short8*)&VlS[e][c8] = *(const short8*)(VbL + (size_t)e * S_ + t0 + c8);
    }
    __syncthreads();
    // ---- QK^T: S = Qh·Kh + Ql·Kh + Qh·Kl ----
    f32x4 acc[2][4];
#pragma unroll
    for (int ns = 0; ns < 4; ++ns) {
      short8 kh0 = *(const short8*)&KhS[ns * 16 + lx][quad * 8];
      short8 kh1 = *(const short8*)&KhS[ns * 16 + lx][32 + quad * 8];
      short8 kl0 = *(const short8*)&KlS[ns * 16 + lx][quad * 8];
      short8 kl1 = *(const short8*)&KlS[ns * 16 + lx][32 + quad * 8];
#pragma unroll
      for (int ms = 0; ms < 2; ++ms) {
        f32x4 a = {};
        a = mfma16(qh[ms][0], kh0, a);
        a = mfma16(ql[ms][0], kh0, a);
        a = mfma16(qh[ms][0], kl0, a);
        a = mfma16(qh[ms][1], kh1, a);
        a = mfma16(ql[ms][1], kh1, a);
        a = mfma16(qh[ms][1], kl1, a);
        acc[ms][ns] = a;
      }
    }
    // ---- one-pass softmax numerator (scores bounded, no max shift), decay into P ----
    const int cse = (t0 + 63 < s0w) ? 0 : ((t0 > s0w + 31) ? 1 : 2);
#pragma unroll
    for (int ms = 0; ms < 2; ++ms)
#pragma unroll
      for (int rg = 0; rg < 4; ++rg) {
        const int rloc = ms * 16 + quad * 4 + rg;
        const int srow = s0w + rloc;
        float pe[4], p[4];
#pragma unroll
        for (int ns = 0; ns < 4; ++ns) pe[ns] = __expf(acc[ms][ns][rg]);
        lsum[ms][rg] += (pe[0] + pe[1]) + (pe[2] + pe[3]);
        if (cse == 0) {           // whole tile strictly below all wave rows
          float rf = exp2f(lg2g * (float)(srow - t0 - 63));
#pragma unroll
          for (int ns = 0; ns < 4; ++ns) p[ns] = pe[ns] * rf * cr[ns];
        } else if (cse == 1) {    // whole tile strictly above
          float rf = exp2f(lg2g * (float)(t0 - srow));
#pragma unroll
          for (int ns = 0; ns < 4; ++ns) p[ns] = pe[ns] * rf * cl[ns];
        } else {                  // mixed (1-2 tiles per wave)
#pragma unroll
          for (int ns = 0; ns < 4; ++ns)
            p[ns] = pe[ns] * exp2f(lg2g * fabsf((float)(srow - (t0 + ns * 16 + lx))));
        }
#pragma unroll
        for (int ns = 0; ns < 4; ++ns)
          PhS[w][rloc][ns * 16 + lx] = (short)bf16h(p[ns]);
      }
    // ---- PV: O += P·(Vh+Vl) ----
    short8 pf[2][2];
#pragma unroll
    for (int ms = 0; ms < 2; ++ms)
#pragma unroll
      for (int kc = 0; kc < 2; ++kc)
        pf[ms][kc] = *(const short8*)&PhS[w][ms * 16 + lx][kc * 32 + quad * 8];
#pragma unroll
    for (int ns = 0; ns < 4; ++ns) {
      short8 vh0 = *(const short8*)&VhS[ns * 16 + lx][quad * 8];
      short8 vh1 = *(const short8*)&VhS[ns * 16 + lx][32 + quad * 8];
      short8 vl0 = *(const short8*)&VlS[ns * 16 + lx][quad * 8];
      short8 vl1 = *(const short8*)&VlS[ns * 16 + lx][32 + quad * 8];
#pragma unroll
      for (int ms = 0; ms < 2; ++ms) {
        f32x4 o = O[ms][ns];
        o = mfma16(pf[ms][0], vh0, o);
        o = mfma16(pf[ms][0], vl0, o);
        o = mfma16(pf[ms][1], vh1, o);
        o = mfma16(pf[ms][1], vl1, o);
        O[ms][ns] = o;
      }
    }
  }
  // ---- deferred l reduction + epilogue ----
#pragma unroll
  for (int ms = 0; ms < 2; ++ms)
#pragma unroll
    for (int rg = 0; rg < 4; ++rg) {
      float s = lsum[ms][rg];
      s += __shfl_xor(s, 1);
      s += __shfl_xor(s, 2);
      s += __shfl_xor(s, 4);
      s += __shfl_xor(s, 8);
      const float inv = 1.0f / s;
      const int srow = s0w + ms * 16 + quad * 4 + rg;
#pragma unroll
      for (int ns = 0; ns < 4; ++ns)
        Y[((size_t)(b * S_ + srow)) * D_ + h * DH_ + ns * 16 + lx] = O[ms][ns][rg] * inv;
    }
}

// ---------- GroupNorm + swish(G) gate -> split bf16 Z [m][512] (row-major, no transpose) ----
__global__ __launch_bounds__(256) void gn_gate_kernel(const float* __restrict__ Y,
                                                      const float* __restrict__ G,
                                                      const float* __restrict__ gnw,
                                                      const float* __restrict__ gnb,
                                                      short* __restrict__ Zh,
                                                      short* __restrict__ Zl) {
  const int r0 = blockIdx.x * 64, h = blockIdx.y, d0 = h * DH_;
  const int tid = threadIdx.x, tx = tid & 15, tyq = tid >> 4;
  float4 wv = *(const float4*)(gnw + d0 + tx * 4);
  float4 bv = *(const float4*)(gnb + d0 + tx * 4);
  float w4[4] = {wv.x, wv.y, wv.z, wv.w};
  float b4[4] = {bv.x, bv.y, bv.z, bv.w};
#pragma unroll
  for (int i = 0; i < 4; ++i) {
    int r = r0 + tyq + i * 16;
    float4 yv = *(const float4*)(Y + (size_t)r * D_ + d0 + tx * 4);
    float y[4] = {yv.x, yv.y, yv.z, yv.w};
    float s = y[0] + y[1] + y[2] + y[3];
    s += __shfl_xor(s, 1); s += __shfl_xor(s, 2); s += __shfl_xor(s, 4); s += __shfl_xor(s, 8);
    const float mu = s * (1.0f / 64.0f);
    float d0_ = y[0] - mu, d1 = y[1] - mu, d2 = y[2] - mu, d3 = y[3] - mu;
    float ss = d0_ * d0_ + d1 * d1 + d2 * d2 + d3 * d3;
    ss += __shfl_xor(ss, 1); ss += __shfl_xor(ss, 2); ss += __shfl_xor(ss, 4); ss += __shfl_xor(ss, 8);
    const float rstd = 1.0f / sqrtf(ss * (1.0f / 64.0f) + 1e-5f);
    float4 gv = *(const float4*)(G + (size_t)r * D_ + d0 + tx * 4);
    float g[4] = {gv.x, gv.y, gv.z, gv.w};
    s16x4 hh, ll;
#pragma unroll
    for (int j = 0; j < 4; ++j) {
      float yn = (y[j] - mu) * rstd * w4[j] + b4[j];
      float sw = g[j] / (1.0f + expf(-g[j]));
      short h_, l_;
      tsplit(sw * yn, h_, l_);
      hh[j] = h_; ll[j] = l_;
    }
    size_t off = (size_t)r * 512 + d0 + tx * 4;
    *(s16x4*)(Zh + off) = hh;
    *(s16x4*)(Zl + off) = ll;
  }
}

extern "C" void kernel_launch(void* const* d_in, const int* in_sizes, int n_in,
                              void* d_out, int out_size, void* d_ws, size_t ws_size,
                              hipStream_t stream) {
  const float* X   = (const float*)d_in[0];
  const float* Wq  = (const float*)d_in[1];
  const float* Wk  = (const float*)d_in[2];
  const float* Wv  = (const float*)d_in[3];
  const float* Wg  = (const float*)d_in[4];
  const float* Wo  = (const float*)d_in[5];
  const float* gnw = (const float*)d_in[6];
  const float* gnb = (const float*)d_in[7];
  float* out = (float*)d_out;
  float* ws  = (float*)d_ws;
  const size_t NB = (size_t)M_ * D_;   // 4M floats = 16 MB per region
  // Region lifetimes (stream-ordered):
  //  R0: Q fp32 -> Krot fp32 -> Zh/Zl
  //  R1: K fp32 -> Y fp32   -> BTo h/l
  //  R2: VhT/VlT (split bf16)
  //  R3: BT fused h/l (4MB) -> Qrot fp32
  //  tab: 0.5MB at ws+4NB   (total 64.5 MB, same as R1/R2 rounds)
  float* R0 = ws;
  float* R1 = ws + NB;
  float* R2 = ws + 2 * NB;
  float* R3 = ws + 3 * NB;
  float* tab = ws + 4 * NB;
  short* BTh = (short*)R3;
  short* BTl = BTh + (size_t)2048 * 512;
  short* VhT = (short*)R2;
  short* VlT = VhT + (size_t)64 * 64 * 1024 / 64 * DH_;   // 8*8*64*1024 = 4M shorts
  short* Zh = (short*)R0;
  short* Zl = Zh + (size_t)M_ * 512;
  short* BToh = (short*)R1;
  short* BTol = BToh + (size_t)512 * 512;

  wprep_kernel<<<dim3(32, 8), 256, 0, stream>>>(Wq, Wk, Wv, Wg, BTh, BTl, 0);
  xpos_table_kernel<<<128, 256, 0, stream>>>(tab);
  gemm_mfma_kernel<false><<<dim3(64, 16), 256, 0, stream>>>(
      X, nullptr, nullptr, BTh, BTl, R0, R1, VhT, VlT, out, 1);
  rotary_ew_kernel<<<4096, 256, 0, stream>>>(R0, R3, tab, 0);   // Q -> Qrot (R3)
  rotary_ew_kernel<<<4096, 256, 0, stream>>>(R1, R0, tab, 1);   // K -> Krot (R0)
  attn_mfma_kernel<<<dim3(8, 64), 256, 0, stream>>>(R3, R0, VhT, VlT, R1);   // -> Y (R1)
  gn_gate_kernel<<<dim3(128, 8), 256, 0, stream>>>(R1, out, gnw, gnb, Zh, Zl);
  wprep_kernel<<<dim3(8, 8), 256, 0, stream>>>(nullptr, nullptr, nullptr, Wo, BToh, BTol, 1);
  gemm_mfma_kernel<true><<<dim3(64, 4), 256, 0, stream>>>(
      nullptr, Zh, Zl, BToh, BTol, nullptr, nullptr, nullptr, nullptr, out, 0);
}

// Round 4
// 241.871 us; speedup vs baseline: 2.8202x; 1.0639x over previous
//
#include <hip/hip_runtime.h>
#include <math.h>

// MultiScaleRetention forward. B=8 S=1024 D=512 H=8 DH=64.
// R4: XCD-aware attention grid (same-bh blocks -> same XCD for K/V L2 reuse),
//     xpos rotary fused into projection-GEMM epilogue (emits pre-split bf16 Q/K),
//     attention staging reduced to pure short8 copies.
#define B_ 8
#define S_ 1024
#define D_ 512
#define H_ 8
#define DH_ 64
#define M_ (B_*S_)   // 8192 rows

typedef __attribute__((ext_vector_type(8))) short short8;
typedef __attribute__((ext_vector_type(4))) short s16x4;
typedef __attribute__((ext_vector_type(4))) float f32x4;

// RNE bf16 (used for P only)
__device__ inline unsigned short bf16h(float x) {
  unsigned u = __float_as_uint(x);
  return (unsigned short)((u + 0x7FFFu + ((u >> 16) & 1u)) >> 16);
}
// trunc split: x = hi + lo + O(2^-16 |x|); x - hi is exact in fp32.
__device__ inline void tsplit(float x, short& hs, short& ls) {
  unsigned u = __float_as_uint(x);
  hs = (short)(u >> 16);
  float r = x - __uint_as_float(u & 0xFFFF0000u);
  ls = (short)(__float_as_uint(r) >> 16);
}
__device__ inline f32x4 mfma16(short8 a, short8 b, f32x4 c) {
  return __builtin_amdgcn_mfma_f32_16x16x32_bf16(a, b, c, 0, 0, 0);
}

// ---------- xpos tables: 4 x [1024][32] = cosQ | sinQ | cosK | sinK ----------
__global__ void xpos_table_kernel(float* __restrict__ tab) {
  int idx = blockIdx.x * 256 + threadIdx.x;
  int s = idx >> 5, i = idx & 31;
  float sv = (2.0f * (float)i + 0.4f * 64.0f) / (1.4f * 64.0f);
  float p = (float)s / 512.0f;
  float scale = powf(sv, p);
  float inv_freq = powf(10000.0f, -((float)i / 32.0f));
  float ang = (float)s * inv_freq;
  float sn = sinf(ang), cs = cosf(ang);
  tab[idx]          = cs * scale;
  tab[32768 + idx]  = sn * scale;
  tab[65536 + idx]  = cs / scale;
  tab[98304 + idx]  = sn / scale;
}

// ---------- weight prep: BT[n][k] split bf16 ----------
__global__ __launch_bounds__(256) void wprep_kernel(
    const float* __restrict__ Wq, const float* __restrict__ Wk,
    const float* __restrict__ Wv, const float* __restrict__ Wg,
    short* __restrict__ BTh, short* __restrict__ BTl, int gonly) {
  __shared__ float t[64][65];
  const int n0 = blockIdx.x * 64, k0 = blockIdx.y * 64;
  const int tid = threadIdx.x;
  const float* src;
  int ld;
  if (gonly) {
    src = Wg + (size_t)k0 * 512 + n0; ld = 512;
  } else {
    int w = n0 >> 9, nn = n0 & 511;
    if (w == 3) { src = Wg + (size_t)k0 * 512 + nn; ld = 512; }
    else {
      const float* W = (w == 0) ? Wq : ((w == 1) ? Wk : Wv);
      int h = nn >> 6;
      src = W + (size_t)h * D_ * DH_ + (size_t)k0 * 64; ld = 64;
    }
  }
#pragma unroll
  for (int i = 0; i < 4; ++i) {
    int idx = tid + i * 256;
    int kk = idx >> 4, nl4 = (idx & 15) * 4;
    float4 v = *(const float4*)(src + (size_t)kk * ld + nl4);
    t[kk][nl4] = v.x; t[kk][nl4 + 1] = v.y; t[kk][nl4 + 2] = v.z; t[kk][nl4 + 3] = v.w;
  }
  __syncthreads();
#pragma unroll
  for (int i = 0; i < 2; ++i) {
    int idx = tid + i * 256;
    int nl = idx >> 3, ck = idx & 7;
    short8 hh, ll;
#pragma unroll
    for (int j = 0; j < 8; ++j) {
      short h_, l_;
      tsplit(t[ck * 8 + j][nl], h_, l_);
      hh[j] = h_; ll[j] = l_;
    }
    size_t off = (size_t)(n0 + nl) * 512 + k0 + ck * 8;
    *(short8*)(BTh + off) = hh;
    *(short8*)(BTl + off) = ll;
  }
}

// ---------- split-bf16 MFMA GEMM: C = A * BT^T. 128x128 tile, BK=32 ----------
// fused: by>>2 = 0:Q 1:K (rotary applied in epilogue, emitted split-bf16 [bh][s][e]),
//        2:V^T split-bf16 [bh][e][s], 3:G fp32 [m][512].  !fused: fp32 out (G ptr).
template<bool PRESPLIT>
__global__ __launch_bounds__(256) void gemm_mfma_kernel(
    const float* __restrict__ Af,
    const short* __restrict__ Ah, const short* __restrict__ Al,
    const short* __restrict__ BTh, const short* __restrict__ BTl,
    const float* __restrict__ tab,
    short* __restrict__ QhO, short* __restrict__ QlO,
    short* __restrict__ KhO, short* __restrict__ KlO,
    short* __restrict__ VhT, short* __restrict__ VlT,
    float* __restrict__ G, int fused) {
  __shared__ __align__(16) short AsH[128][40];
  __shared__ __align__(16) short AsL[128][40];
  __shared__ __align__(16) short BsH[128][40];
  __shared__ __align__(16) short BsL[128][40];
  const int m0 = blockIdx.x * 128, by = blockIdx.y, n0 = by * 128;
  const int tid = threadIdx.x, w = tid >> 6, lane = tid & 63;
  const int lx = lane & 15, quad = lane >> 4;
  const int wr = w >> 1, wc = w & 1;
  f32x4 acc[4][4] = {};
  for (int k0 = 0; k0 < 512; k0 += 32) {
    if constexpr (PRESPLIT) {
#pragma unroll
      for (int i = 0; i < 2; ++i) {
        int idx = tid + i * 256;
        int r = idx >> 2, sg = (idx & 3) * 8;
        *(short8*)&AsH[r][sg] = *(const short8*)(Ah + (size_t)(m0 + r) * 512 + k0 + sg);
        *(short8*)&AsL[r][sg] = *(const short8*)(Al + (size_t)(m0 + r) * 512 + k0 + sg);
      }
    } else {
      int r = tid >> 1, kh = (tid & 1) * 16;
      const float* ap = Af + (size_t)(m0 + r) * 512 + k0 + kh;
#pragma unroll
      for (int j4 = 0; j4 < 4; ++j4) {
        float4 v = *(const float4*)(ap + j4 * 4);
        s16x4 hh, ll;
        short h_, l_;
        tsplit(v.x, h_, l_); hh[0] = h_; ll[0] = l_;
        tsplit(v.y, h_, l_); hh[1] = h_; ll[1] = l_;
        tsplit(v.z, h_, l_); hh[2] = h_; ll[2] = l_;
        tsplit(v.w, h_, l_); hh[3] = h_; ll[3] = l_;
        *(s16x4*)&AsH[r][kh + j4 * 4] = hh;
        *(s16x4*)&AsL[r][kh + j4 * 4] = ll;
      }
    }
#pragma unroll
    for (int i = 0; i < 2; ++i) {
      int idx = tid + i * 256;
      int r = idx >> 2, sg = (idx & 3) * 8;
      *(short8*)&BsH[r][sg] = *(const short8*)(BTh + (size_t)(n0 + r) * 512 + k0 + sg);
      *(short8*)&BsL[r][sg] = *(const short8*)(BTl + (size_t)(n0 + r) * 512 + k0 + sg);
    }
    __syncthreads();
    short8 fah[4], fal[4], fbh[4], fbl[4];
#pragma unroll
    for (int i = 0; i < 4; ++i) {
      fah[i] = *(const short8*)&AsH[wr * 64 + i * 16 + lx][quad * 8];
      fal[i] = *(const short8*)&AsL[wr * 64 + i * 16 + lx][quad * 8];
      fbh[i] = *(const short8*)&BsH[wc * 64 + i * 16 + lx][quad * 8];
      fbl[i] = *(const short8*)&BsL[wc * 64 + i * 16 + lx][quad * 8];
    }
#pragma unroll
    for (int ms = 0; ms < 4; ++ms)
#pragma unroll
      for (int ns = 0; ns < 4; ++ns) {
        f32x4 a = acc[ms][ns];
        a = mfma16(fah[ms], fbh[ns], a);
        a = mfma16(fal[ms], fbh[ns], a);
        a = mfma16(fah[ms], fbl[ns], a);
        acc[ms][ns] = a;
      }
    __syncthreads();
  }
  // ---- epilogue ----
  if (fused) {
    const int w4 = by >> 2;
    const int ncb = (by & 3) * 128 + wc * 64;   // within 512
    if (w4 < 2) {
      // xpos rotary (pair partner is lane lx^1) + trunc-split store
      short* Ph = (w4 == 0) ? QhO : KhO;
      short* Pl = (w4 == 0) ? QlO : KlO;
      const float* ct = tab + (w4 ? 65536 : 0);
      const float* st = tab + (w4 ? 98304 : 32768);
#pragma unroll
      for (int ms = 0; ms < 4; ++ms) {
        const int m = m0 + wr * 64 + ms * 16 + quad * 4;
        const int b = m >> 10, sbase = m & 1023;
#pragma unroll
        for (int ns = 0; ns < 4; ++ns) {
          const int n = ncb + ns * 16 + lx;
          const int h = n >> 6, e = n & 63;
          const int i0 = e >> 1;
          const float sgn = (e & 1) ? 1.0f : -1.0f;
          short* ph = Ph + (((size_t)(b * 8 + h)) * 1024 + sbase) * 64 + e;
          short* pl = Pl + (((size_t)(b * 8 + h)) * 1024 + sbase) * 64 + e;
#pragma unroll
          for (int rg = 0; rg < 4; ++rg) {
            const int s = sbase + rg;
            float v = acc[ms][ns][rg];
            float vp = __shfl_xor(v, 1);
            float o = v * ct[s * 32 + i0] + sgn * vp * st[s * 32 + i0];
            short h_, l_;
            tsplit(o, h_, l_);
            ph[rg * 64] = h_;
            pl[rg * 64] = l_;
          }
        }
      }
    } else if (w4 == 2) {
#pragma unroll
      for (int ms = 0; ms < 4; ++ms) {
        const int m = m0 + wr * 64 + ms * 16 + quad * 4;
        const int b = m >> 10, s = m & 1023;
#pragma unroll
        for (int ns = 0; ns < 4; ++ns) {
          const int n = ncb + ns * 16 + lx;
          const int h = n >> 6, e = n & 63;
          s16x4 hh, ll;
#pragma unroll
          for (int rg = 0; rg < 4; ++rg) {
            short h_, l_;
            tsplit(acc[ms][ns][rg], h_, l_);
            hh[rg] = h_; ll[rg] = l_;
          }
          size_t off = (((size_t)(b * 8 + h)) * 64 + e) * 1024 + s;
          *(s16x4*)(VhT + off) = hh;
          *(s16x4*)(VlT + off) = ll;
        }
      }
    } else {
#pragma unroll
      for (int ms = 0; ms < 4; ++ms) {
        const int m = m0 + wr * 64 + ms * 16 + quad * 4;
#pragma unroll
        for (int ns = 0; ns < 4; ++ns) {
          const int n = ncb + ns * 16 + lx;
#pragma unroll
          for (int rg = 0; rg < 4; ++rg) G[(size_t)(m + rg) * 512 + n] = acc[ms][ns][rg];
        }
      }
    }
  } else {
#pragma unroll
    for (int ms = 0; ms < 4; ++ms) {
      const int m = m0 + wr * 64 + ms * 16 + quad * 4;
#pragma unroll
      for (int ns = 0; ns < 4; ++ns) {
        const int n = n0 + wc * 64 + ns * 16 + lx;
#pragma unroll
        for (int rg = 0; rg < 4; ++rg) G[(size_t)(m + rg) * 512 + n] = acc[ms][ns][rg];
      }
    }
  }
}

// ---------- attention: split-bf16 MFMA, one-pass softmax, factored decay ----------
// grid (64, 8): x = bh (same-bh s-blocks land on same XCD via round-robin), y = s-tile.
__global__ __launch_bounds__(256, 2) void attn_mfma_kernel(
    const short* __restrict__ Qh, const short* __restrict__ Ql,
    const short* __restrict__ Kh, const short* __restrict__ Kl,
    const short* __restrict__ VhT, const short* __restrict__ VlT,
    float* __restrict__ Y) {
  __shared__ __align__(16) short KhS[64][72];     // [t][e]
  __shared__ __align__(16) short KlS[64][72];
  __shared__ __align__(16) short VhS[64][72];     // [e][t]
  __shared__ __align__(16) short VlS[64][72];
  __shared__ __align__(16) short PhS[4][32][72];  // per-wave [s][t]
  const int bh = blockIdx.x, s0 = blockIdx.y * 128;
  const int b = bh >> 3, h = bh & 7;
  const int tid = threadIdx.x;
  const int w = tid >> 6, lane = tid & 63;
  const int lx = lane & 15, quad = lane >> 4;
  const int s0w = s0 + w * 32;
  const float l0c = -3.4657359027997265f;   // ln(1/32)
  const float l1c = -6.2383246250395075f;   // ln(1/512)
  const float gamma = 1.0f - expf(l0c + (float)h * (l1c - l0c) / 7.0f);
  const float lg2g = log2f(gamma);
  const short* Qbh = Qh + (size_t)bh * S_ * DH_;
  const short* Qbl = Ql + (size_t)bh * S_ * DH_;
  const short* Kbh = Kh + (size_t)bh * S_ * DH_;
  const short* Kbl = Kl + (size_t)bh * S_ * DH_;
  const short* VbH = VhT + (size_t)bh * DH_ * S_;
  const short* VbL = VlT + (size_t)bh * DH_ * S_;

  float cl[4], cr[4];
#pragma unroll
  for (int ns = 0; ns < 4; ++ns) {
    cl[ns] = exp2f(lg2g * (float)(ns * 16 + lx));
    cr[ns] = exp2f(lg2g * (float)(63 - ns * 16 - lx));
  }

  // Q A-fragments straight from global (pre-split by GEMM epilogue)
  short8 qfh[2][2], qfl[2][2];
#pragma unroll
  for (int ms = 0; ms < 2; ++ms)
#pragma unroll
    for (int kc = 0; kc < 2; ++kc) {
      size_t off = (size_t)(s0w + ms * 16 + lx) * DH_ + kc * 32 + quad * 8;
      qfh[ms][kc] = *(const short8*)(Qbh + off);
      qfl[ms][kc] = *(const short8*)(Qbl + off);
    }

  f32x4 O[2][4] = {};
  float lsum[2][4] = {};

  for (int t0 = 0; t0 < S_; t0 += 64) {
    __syncthreads();
    // ---- stage K/V: pure short8 copies, b128 writes ----
#pragma unroll
    for (int i = 0; i < 2; ++i) {
      int slot = tid + i * 256;          // 0..511
      int r = slot >> 3, c8 = (slot & 7) * 8;
      *(short8*)&KhS[r][c8] = *(const short8*)(Kbh + (size_t)(t0 + r) * DH_ + c8);
      *(short8*)&KlS[r][c8] = *(const short8*)(Kbl + (size_t)(t0 + r) * DH_ + c8);
      *(short8*)&VhS[r][c8] = *(const short8*)(VbH + (size_t)r * S_ + t0 + c8);
      *(short8*)&VlS[r][c8] = *(const short8*)(VbL + (size_t)r * S_ + t0 + c8);
    }
    __syncthreads();
    // ---- QK^T: S = Qh·Kh + Ql·Kh + Qh·Kl ----
    f32x4 acc[2][4];
#pragma unroll
    for (int ns = 0; ns < 4; ++ns) {
      short8 kh0 = *(const short8*)&KhS[ns * 16 + lx][quad * 8];
      short8 kh1 = *(const short8*)&KhS[ns * 16 + lx][32 + quad * 8];
      short8 kl0 = *(const short8*)&KlS[ns * 16 + lx][quad * 8];
      short8 kl1 = *(const short8*)&KlS[ns * 16 + lx][32 + quad * 8];
#pragma unroll
      for (int ms = 0; ms < 2; ++ms) {
        f32x4 a = {};
        a = mfma16(qfh[ms][0], kh0, a);
        a = mfma16(qfl[ms][0], kh0, a);
        a = mfma16(qfh[ms][0], kl0, a);
        a = mfma16(qfh[ms][1], kh1, a);
        a = mfma16(qfl[ms][1], kh1, a);
        a = mfma16(qfh[ms][1], kl1, a);
        acc[ms][ns] = a;
      }
    }
    // ---- one-pass softmax numerator (bounded scores), decay into P ----
    const int cse = (t0 + 63 < s0w) ? 0 : ((t0 > s0w + 31) ? 1 : 2);
#pragma unroll
    for (int ms = 0; ms < 2; ++ms)
#pragma unroll
      for (int rg = 0; rg < 4; ++rg) {
        const int rloc = ms * 16 + quad * 4 + rg;
        const int srow = s0w + rloc;
        float pe[4], p[4];
#pragma unroll
        for (int ns = 0; ns < 4; ++ns) pe[ns] = __expf(acc[ms][ns][rg]);
        lsum[ms][rg] += (pe[0] + pe[1]) + (pe[2] + pe[3]);
        if (cse == 0) {
          float rf = exp2f(lg2g * (float)(srow - t0 - 63));
#pragma unroll
          for (int ns = 0; ns < 4; ++ns) p[ns] = pe[ns] * rf * cr[ns];
        } else if (cse == 1) {
          float rf = exp2f(lg2g * (float)(t0 - srow));
#pragma unroll
          for (int ns = 0; ns < 4; ++ns) p[ns] = pe[ns] * rf * cl[ns];
        } else {
#pragma unroll
          for (int ns = 0; ns < 4; ++ns)
            p[ns] = pe[ns] * exp2f(lg2g * fabsf((float)(srow - (t0 + ns * 16 + lx))));
        }
#pragma unroll
        for (int ns = 0; ns < 4; ++ns)
          PhS[w][rloc][ns * 16 + lx] = (short)bf16h(p[ns]);
      }
    // ---- PV: O += P·(Vh+Vl) ----
    short8 pf[2][2];
#pragma unroll
    for (int ms = 0; ms < 2; ++ms)
#pragma unroll
      for (int kc = 0; kc < 2; ++kc)
        pf[ms][kc] = *(const short8*)&PhS[w][ms * 16 + lx][kc * 32 + quad * 8];
#pragma unroll
    for (int ns = 0; ns < 4; ++ns) {
      short8 vh0 = *(const short8*)&VhS[ns * 16 + lx][quad * 8];
      short8 vh1 = *(const short8*)&VhS[ns * 16 + lx][32 + quad * 8];
      short8 vl0 = *(const short8*)&VlS[ns * 16 + lx][quad * 8];
      short8 vl1 = *(const short8*)&VlS[ns * 16 + lx][32 + quad * 8];
#pragma unroll
      for (int ms = 0; ms < 2; ++ms) {
        f32x4 o = O[ms][ns];
        o = mfma16(pf[ms][0], vh0, o);
        o = mfma16(pf[ms][0], vl0, o);
        o = mfma16(pf[ms][1], vh1, o);
        o = mfma16(pf[ms][1], vl1, o);
        O[ms][ns] = o;
      }
    }
  }
  // ---- deferred l reduction + epilogue ----
#pragma unroll
  for (int ms = 0; ms < 2; ++ms)
#pragma unroll
    for (int rg = 0; rg < 4; ++rg) {
      float s = lsum[ms][rg];
      s += __shfl_xor(s, 1);
      s += __shfl_xor(s, 2);
      s += __shfl_xor(s, 4);
      s += __shfl_xor(s, 8);
      const float inv = 1.0f / s;
      const int srow = s0w + ms * 16 + quad * 4 + rg;
#pragma unroll
      for (int ns = 0; ns < 4; ++ns)
        Y[((size_t)(b * S_ + srow)) * D_ + h * DH_ + ns * 16 + lx] = O[ms][ns][rg] * inv;
    }
}

// ---------- GroupNorm + swish(G) gate -> split bf16 Z [m][512] ----------
__global__ __launch_bounds__(256) void gn_gate_kernel(const float* __restrict__ Y,
                                                      const float* __restrict__ G,
                                                      const float* __restrict__ gnw,
                                                      const float* __restrict__ gnb,
                                                      short* __restrict__ Zh,
                                                      short* __restrict__ Zl) {
  const int r0 = blockIdx.x * 64, h = blockIdx.y, d0 = h * DH_;
  const int tid = threadIdx.x, tx = tid & 15, tyq = tid >> 4;
  float4 wv = *(const float4*)(gnw + d0 + tx * 4);
  float4 bv = *(const float4*)(gnb + d0 + tx * 4);
  float w4[4] = {wv.x, wv.y, wv.z, wv.w};
  float b4[4] = {bv.x, bv.y, bv.z, bv.w};
#pragma unroll
  for (int i = 0; i < 4; ++i) {
    int r = r0 + tyq + i * 16;
    float4 yv = *(const float4*)(Y + (size_t)r * D_ + d0 + tx * 4);
    float y[4] = {yv.x, yv.y, yv.z, yv.w};
    float s = y[0] + y[1] + y[2] + y[3];
    s += __shfl_xor(s, 1); s += __shfl_xor(s, 2); s += __shfl_xor(s, 4); s += __shfl_xor(s, 8);
    const float mu = s * (1.0f / 64.0f);
    float d0_ = y[0] - mu, d1 = y[1] - mu, d2 = y[2] - mu, d3 = y[3] - mu;
    float ss = d0_ * d0_ + d1 * d1 + d2 * d2 + d3 * d3;
    ss += __shfl_xor(ss, 1); ss += __shfl_xor(ss, 2); ss += __shfl_xor(ss, 4); ss += __shfl_xor(ss, 8);
    const float rstd = 1.0f / sqrtf(ss * (1.0f / 64.0f) + 1e-5f);
    float4 gv = *(const float4*)(G + (size_t)r * D_ + d0 + tx * 4);
    float g[4] = {gv.x, gv.y, gv.z, gv.w};
    s16x4 hh, ll;
#pragma unroll
    for (int j = 0; j < 4; ++j) {
      float yn = (y[j] - mu) * rstd * w4[j] + b4[j];
      float sw = g[j] / (1.0f + expf(-g[j]));
      short h_, l_;
      tsplit(sw * yn, h_, l_);
      hh[j] = h_; ll[j] = l_;
    }
    size_t off = (size_t)r * 512 + d0 + tx * 4;
    *(s16x4*)(Zh + off) = hh;
    *(s16x4*)(Zl + off) = ll;
  }
}

extern "C" void kernel_launch(void* const* d_in, const int* in_sizes, int n_in,
                              void* d_out, int out_size, void* d_ws, size_t ws_size,
                              hipStream_t stream) {
  const float* X   = (const float*)d_in[0];
  const float* Wq  = (const float*)d_in[1];
  const float* Wk  = (const float*)d_in[2];
  const float* Wv  = (const float*)d_in[3];
  const float* Wg  = (const float*)d_in[4];
  const float* Wo  = (const float*)d_in[5];
  const float* gnw = (const float*)d_in[6];
  const float* gnb = (const float*)d_in[7];
  float* out = (float*)d_out;
  float* ws  = (float*)d_ws;
  const size_t NB = (size_t)M_ * D_;   // 4M elems; 16 MB as fp32, 8 MB as shorts
  // Region lifetimes (stream-ordered):
  //  R0: Qh/Ql (gemm epi) -> Zh/Zl
  //  R1: Kh/Kl            -> BToh/BTol
  //  R2: VhT/VlT
  //  R3: BT fused         -> Y fp32
  float* R0 = ws;
  float* R1 = ws + NB;
  float* R2 = ws + 2 * NB;
  float* R3 = ws + 3 * NB;
  float* tab = ws + 4 * NB;
  short* BTh = (short*)R3;
  short* BTl = BTh + (size_t)2048 * 512;
  short* Qh = (short*)R0;  short* Ql = Qh + NB;
  short* Kh = (short*)R1;  short* Kl = Kh + NB;
  short* VhT = (short*)R2; short* VlT = VhT + NB;
  float* Yb = R3;
  short* Zh = (short*)R0;  short* Zl = Zh + NB;
  short* BToh = (short*)R1;
  short* BTol = BToh + (size_t)512 * 512;

  wprep_kernel<<<dim3(32, 8), 256, 0, stream>>>(Wq, Wk, Wv, Wg, BTh, BTl, 0);
  xpos_table_kernel<<<128, 256, 0, stream>>>(tab);
  gemm_mfma_kernel<false><<<dim3(64, 16), 256, 0, stream>>>(
      X, nullptr, nullptr, BTh, BTl, tab, Qh, Ql, Kh, Kl, VhT, VlT, out, 1);
  attn_mfma_kernel<<<dim3(64, 8), 256, 0, stream>>>(Qh, Ql, Kh, Kl, VhT, VlT, Yb);
  gn_gate_kernel<<<dim3(128, 8), 256, 0, stream>>>(Yb, out, gnw, gnb, Zh, Zl);
  wprep_kernel<<<dim3(8, 8), 256, 0, stream>>>(nullptr, nullptr, nullptr, Wo, BToh, BTol, 1);
  gemm_mfma_kernel<true><<<dim3(64, 4), 256, 0, stream>>>(
      nullptr, Zh, Zl, BToh, BTol, nullptr, nullptr, nullptr, nullptr, nullptr,
      nullptr, nullptr, out, 0);
}